// Round 2
// baseline (748.975 us; speedup 1.0000x reference)
//
#include <hip/hip_runtime.h>
#include <hip/hip_bf16.h>

#define H 1024
#define B 32
#define S 2048

typedef __attribute__((ext_vector_type(8))) short bf16x8;
typedef __attribute__((ext_vector_type(4))) float f32x4;

union U4 { uint4 u; bf16x8 b; };

__device__ __forceinline__ unsigned short f2bf(float f) {
    unsigned u = __float_as_uint(f);
    unsigned r = (u + 0x7fffu + ((u >> 16) & 1u)) >> 16;
    return (unsigned short)r;
}

__device__ __forceinline__ uint4 pack8(float4 x, float4 y) {
    uint4 p;
    p.x = (unsigned)f2bf(x.x) | ((unsigned)f2bf(x.y) << 16);
    p.y = (unsigned)f2bf(x.z) | ((unsigned)f2bf(x.w) << 16);
    p.z = (unsigned)f2bf(y.x) | ((unsigned)f2bf(y.y) << 16);
    p.w = (unsigned)f2bf(y.z) | ((unsigned)f2bf(y.w) << 16);
    return p;
}

__device__ __forceinline__ float ftanh(float x) {
    float x2 = __builtin_amdgcn_fmed3f(x + x, -30.f, 30.f);
    float e = __expf(x2);
    return 1.f - 2.f * __builtin_amdgcn_rcpf(e + 1.f);
}

__device__ __forceinline__ void async_copy16(const void* g, void* l) {
    __builtin_amdgcn_global_load_lds(
        (const __attribute__((address_space(1))) unsigned int*)g,
        (__attribute__((address_space(3))) unsigned int*)l, 16, 0, 0);
}

// ---------------------------------------------------------------------------
// K0: Ua_w fp32 [n][k] -> bf16 MFMA-B-frag order: UaSw[nb(8)][kc(32)][nt(8)*64+lane]
__global__ void k0_swizzle(const float* __restrict__ Ua, uint4* __restrict__ UaSw) {
    int t = blockIdx.x * 256 + threadIdx.x;   // 0..131071
    int lane = t & 63;
    int nt = (t >> 6) & 7;
    int kc = (t >> 9) & 31;
    int nb = t >> 14;
    int n = nb * 128 + nt * 16 + (lane & 15);
    int k = kc * 32 + ((lane >> 4) & 3) * 8;
    const float4* src = (const float4*)(Ua + (size_t)n * H + k);
    UaSw[t] = pack8(src[0], src[1]);
}

// ---------------------------------------------------------------------------
// KA: keys fp32 [b*S+s][h] -> bf16 MFMA A-frag order:
// Abf[g], g = (stile*32 + kc)*64 + lane; stile = (b*S+s)/16
// row = stile*16 + (lane&15); col = kc*32 + ((lane>>4)&3)*8 + j
__global__ __launch_bounds__(256) void ka_swz(const float* __restrict__ keys,
                                              uint4* __restrict__ Abf) {
    size_t g = (size_t)blockIdx.x * 256 + threadIdx.x;   // 0..8388607
    int lane = (int)(g & 63);
    size_t u = g >> 6;
    int kc = (int)(u & 31);
    size_t stile = u >> 5;                                // 0..4095
    size_t row = stile * 16 + (lane & 15);
    int col = kc * 32 + ((lane >> 4) & 3) * 8;
    const float4* src = (const float4*)(keys + row * H + col);
    Abf[g] = pack8(src[0], src[1]);
}

// ---------------------------------------------------------------------------
// K1: qp[b][n] = sum_h query[b][h]*Wa_w[n][h] + Wa_b[n] + Ua_b[n]
__global__ __launch_bounds__(256) void k1_qproj(
    const float* __restrict__ q, const float* __restrict__ Wa,
    const float* __restrict__ Wab, const float* __restrict__ Uab,
    float* __restrict__ qp) {
    int b = blockIdx.y;
    int t = threadIdx.x;
    int n = blockIdx.x * 64 + (t >> 2);
    int quarter = t & 3;
    __shared__ float qs[H];
    for (int i = t; i < H; i += 256) qs[i] = q[b * H + i];
    __syncthreads();
    const float4* wr = (const float4*)(Wa + (size_t)n * H + quarter * 256);
    const float* qq = qs + quarter * 256;
    float acc = 0.f;
#pragma unroll 4
    for (int i = 0; i < 64; i++) {
        float4 w = wr[i];
        acc += qq[i * 4 + 0] * w.x + qq[i * 4 + 1] * w.y +
               qq[i * 4 + 2] * w.z + qq[i * 4 + 3] * w.w;
    }
    acc += __shfl_xor(acc, 1, 64);
    acc += __shfl_xor(acc, 2, 64);
    if (quarter == 0) qp[b * H + n] = acc + Wab[n] + Uab[n];
}

// ---------------------------------------------------------------------------
// K2v4: LDS-staged 256x256-tile GEMM with counted-vmcnt pipeline (T3+T4+T5).
// 512 threads = 8 waves (2M x 4N); per-wave C = 128x64 (acc[8][4] f32x4).
// BK=32 = one frag unit; K-tile = A 16KB + B 16KB = 32KB; 4 LDS buffers
// (128KB), prefetch distance 3. Per step each wave issues exactly 4
// global_load_lds (waves 0-3: A chunks, waves 4-7: B chunks) -> boundary
// wait is s_waitcnt vmcnt(8) (= 2 tiles in flight x 4 loads), never 0.
// Inputs are pre-swizzled to linear MFMA-frag order (ka_swz / k0_swizzle),
// so global_load_lds's linear lane*16 dest is exactly the frag layout and
// ds_read_b128 at lane*16 is conflict-free (m97 pattern, no XOR needed).
// Hazard: step t stages into buf[(t+3)&3] == buf[(t-1)&3]; safe because the
// boundary barrier of step t is crossed only after every wave's ds_reads of
// buf[(t-1)&3] completed (sched_barrier(0) pins reads+MFMA before barrier).
__global__ __launch_bounds__(512, 2) void k2_scores3(
    const uint4* __restrict__ Abf, const uint4* __restrict__ UaSw,
    const float* __restrict__ qp, const float* __restrict__ Vaw,
    float* __restrict__ sp) {
    extern __shared__ uint4 bufs[];          // 4 x 2048 uint4 = 128 KB
    const int tid = threadIdx.x;
    const int lane = tid & 63;
    const int w = tid >> 6;                  // 0..7
    const int wm = w >> 2;                   // 0..1
    const int wn = w & 3;                    // 0..3

    const int lid = blockIdx.x;              // 0..1023
    const int c = lid & 7;                   // XCD slot
    const int qidx = lid >> 3;               // 0..127
    const int nblk = qidx & 3;               // N-block (256 cols)
    const int mb = (qidx >> 2) * 8 + c;      // 0..255 (256 rows each)
    const int b = mb >> 3;                   // 8 m-blocks per batch row
    const int stile0 = mb * 16;

    f32x4 acc[8][4];
#pragma unroll
    for (int mt = 0; mt < 8; mt++)
#pragma unroll
        for (int nt = 0; nt < 4; nt++) acc[mt][nt] = (f32x4){0.f, 0.f, 0.f, 0.f};

    // stage tile kt into LDS buffer tb: 32 chunks of 1KB, 4 per wave
    auto STAGE = [&](int kt, int tb) {
        uint4* dst = bufs + tb * 2048;
        if (w < 4) {
#pragma unroll
            for (int i = 0; i < 4; i++) {
                int st = w * 4 + i;
                async_copy16(Abf + ((size_t)(stile0 + st) * 32 + kt) * 64 + lane,
                             dst + st * 64 + lane);
            }
        } else {
#pragma unroll
            for (int i = 0; i < 4; i++) {
                int nt = (w - 4) * 4 + i;
                int nbu = nblk * 2 + (nt >> 3);
                async_copy16(UaSw + (size_t)nbu * 16384 + (size_t)kt * 512 +
                                 (nt & 7) * 64 + lane,
                             dst + 1024 + nt * 64 + lane);
            }
        }
    };

    // prologue: tiles 0,1,2 in flight (12 loads); vmcnt(8) -> tile 0 landed
    STAGE(0, 0);
    __builtin_amdgcn_sched_barrier(0);
    STAGE(1, 1);
    __builtin_amdgcn_sched_barrier(0);
    STAGE(2, 2);
    __builtin_amdgcn_sched_barrier(0);
    asm volatile("s_waitcnt vmcnt(8)" ::: "memory");
    __builtin_amdgcn_s_barrier();
    __builtin_amdgcn_sched_barrier(0);

#pragma unroll 4
    for (int t = 0; t < 32; t++) {
        // issue next prefetch (tile t+3, wraps: redundant re-stage of 0..2 at tail)
        STAGE((t + 3) & 31, (t + 3) & 3);

        const uint4* cur = bufs + (t & 3) * 2048;
        U4 a[8], bb[4];
#pragma unroll
        for (int mt = 0; mt < 8; mt++) a[mt].u = cur[(wm * 8 + mt) * 64 + lane];
#pragma unroll
        for (int nt = 0; nt < 4; nt++) bb[nt].u = cur[1024 + (wn * 4 + nt) * 64 + lane];

        __builtin_amdgcn_s_setprio(1);
#pragma unroll
        for (int mt = 0; mt < 8; mt++)
#pragma unroll
            for (int nt = 0; nt < 4; nt++)
                acc[mt][nt] = __builtin_amdgcn_mfma_f32_16x16x32_bf16(
                    a[mt].b, bb[nt].b, acc[mt][nt], 0, 0, 0);
        __builtin_amdgcn_s_setprio(0);

        // boundary: tile t+1 (issued 3 steps ago) guaranteed landed; 8 newest
        // loads (tiles t+2,t+3) stay in flight across the barrier.
        __builtin_amdgcn_sched_barrier(0);
        asm volatile("s_waitcnt vmcnt(8)" ::: "memory");
        __builtin_amdgcn_s_barrier();
        __builtin_amdgcn_sched_barrier(0);
    }

    // epilogue: tanh + dot Va + col-reduce; 16 partial planes (nblk*4+wn)
    const int col = lane & 15, qd = lane >> 4;
    float qv[4], vv[4];
#pragma unroll
    for (int nt = 0; nt < 4; nt++) {
        int n = nblk * 256 + (wn * 4 + nt) * 16 + col;
        qv[nt] = qp[b * H + n];
        vv[nt] = Vaw[n];
    }
    const int plane = nblk * 4 + wn;
#pragma unroll
    for (int mt = 0; mt < 8; mt++) {
        float rs[4] = {0.f, 0.f, 0.f, 0.f};
#pragma unroll
        for (int nt = 0; nt < 4; nt++)
#pragma unroll
            for (int r = 0; r < 4; r++)
                rs[r] += ftanh(acc[mt][nt][r] + qv[nt]) * vv[nt];
#pragma unroll
        for (int r = 0; r < 4; r++) {
            float v = rs[r];
            v += __shfl_xor(v, 1, 64);
            v += __shfl_xor(v, 2, 64);
            v += __shfl_xor(v, 4, 64);
            v += __shfl_xor(v, 8, 64);
            if (col == 0)
                sp[(size_t)plane * (B * S) + mb * 256 +
                   (wm * 8 + mt) * 16 + qd * 4 + r] = v;
        }
    }
}

// ---------------------------------------------------------------------------
// K4v3: fused partial-sum (16 planes) + softmax + weights-write + context.
// grid (8,32): block (kcg,b); wave wv handles kc=kcg*4+wv.
__global__ __launch_bounds__(256) void k4_ctx2(const uint4* __restrict__ Abf,
                                               const float* __restrict__ sp,
                                               float* __restrict__ out) {
    int kcg = blockIdx.x, b = blockIdx.y;
    int t = threadIdx.x;
    __shared__ float red[256];
    __shared__ float wl[S];   // 8 KB

    float v[8];
#pragma unroll
    for (int i = 0; i < 8; i++) {
        int s = i * 256 + t;
        float sum = 0.f;
#pragma unroll
        for (int nb = 0; nb < 16; nb++) sum += sp[(size_t)nb * B * S + b * S + s];
        v[i] = sum;
    }
    float lm = -1e30f;
#pragma unroll
    for (int i = 0; i < 8; i++) lm = fmaxf(lm, v[i]);
    red[t] = lm;
    __syncthreads();
    for (int s = 128; s > 0; s >>= 1) {
        if (t < s) red[t] = fmaxf(red[t], red[t + s]);
        __syncthreads();
    }
    float m = red[0];
    __syncthreads();
    float ls = 0.f;
#pragma unroll
    for (int i = 0; i < 8; i++) ls += __expf(v[i] - m);
    red[t] = ls;
    __syncthreads();
    for (int s = 128; s > 0; s >>= 1) {
        if (t < s) red[t] += red[t + s];
        __syncthreads();
    }
    float inv = 1.f / red[0];
#pragma unroll
    for (int i = 0; i < 8; i++) {
        int s = i * 256 + t;
        float w = __expf(v[i] - m) * inv;
        wl[s] = w;
        if (kcg == 0) out[B * H + b * S + s] = w;
    }
    __syncthreads();

    const int wv = t >> 6, lane = t & 63, qd = lane >> 4, colr = lane & 15;
    const int kc = kcg * 4 + wv;
    float a8[8] = {0.f, 0.f, 0.f, 0.f, 0.f, 0.f, 0.f, 0.f};
    const uint4* base = Abf + ((size_t)(b * 128) * 32 + kc) * 64 + lane;
#pragma unroll 4
    for (int st = 0; st < 128; st++) {
        uint4 f = base[(size_t)st * 2048];
        float w = wl[st * 16 + colr];
        a8[0] += w * __uint_as_float(f.x << 16);
        a8[1] += w * __uint_as_float(f.x & 0xffff0000u);
        a8[2] += w * __uint_as_float(f.y << 16);
        a8[3] += w * __uint_as_float(f.y & 0xffff0000u);
        a8[4] += w * __uint_as_float(f.z << 16);
        a8[5] += w * __uint_as_float(f.z & 0xffff0000u);
        a8[6] += w * __uint_as_float(f.w << 16);
        a8[7] += w * __uint_as_float(f.w & 0xffff0000u);
    }
#pragma unroll
    for (int j = 0; j < 8; j++) {
        float vj = a8[j];
        vj += __shfl_xor(vj, 1, 64);
        vj += __shfl_xor(vj, 2, 64);
        vj += __shfl_xor(vj, 4, 64);
        vj += __shfl_xor(vj, 8, 64);
        a8[j] = vj;
    }
    if (colr == 0) {
        int colbase = kc * 32 + qd * 8;
#pragma unroll
        for (int j = 0; j < 8; j++) out[b * H + colbase + j] = a8[j];
    }
}

// ===========================================================================
// Fallback path (ws too small): round-4 kernels (8 partial planes)
// ===========================================================================
__global__ __launch_bounds__(256, 3) void k2_scores_fb(
    const float* __restrict__ keys, const uint4* __restrict__ UaSw,
    const float* __restrict__ qp, const float* __restrict__ Vaw,
    float* __restrict__ sp) {
    __shared__ uint4 As[2][512];
    __shared__ uint4 Bs[2][512];
    __shared__ float part[2][128];
    const int tid = threadIdx.x;
    const int lane = tid & 63;
    const int wave = tid >> 6;
    const int wm = wave >> 1, wn = wave & 1;
    const int lid = blockIdx.x;
    const int c = lid & 7;
    const int qq = lid >> 3;
    const int nb = qq & 7;
    const int mb = (qq >> 3) * 8 + c;
    const int b = mb >> 4;
    const int s0 = (mb & 15) << 7;
    const int el = tid & 63;
    const int srow0 = s0 + (tid >> 6) * 16 + (el & 15);
    const int srow1 = srow0 + 64;
    const int kofs = ((el >> 4) & 3) * 8;
    const float4* ka0 = (const float4*)(keys + ((size_t)b * S + srow0) * H + kofs);
    const float4* ka1 = (const float4*)(keys + ((size_t)b * S + srow1) * H + kofs);
    const uint4* srcB = UaSw + (size_t)nb * 32 * 512;
    f32x4 acc[4][4];
#pragma unroll
    for (int mt = 0; mt < 4; mt++)
#pragma unroll
        for (int nt = 0; nt < 4; nt++) acc[mt][nt] = (f32x4){0.f, 0.f, 0.f, 0.f};
    float4 x0 = ka0[0], y0 = ka0[1], x1 = ka1[0], y1 = ka1[1];
    async_copy16(srcB + tid,       &Bs[0][tid]);
    async_copy16(srcB + tid + 256, &Bs[0][tid + 256]);
    As[0][tid]       = pack8(x0, y0);
    As[0][tid + 256] = pack8(x1, y1);
    x0 = ka0[8]; y0 = ka0[9]; x1 = ka1[8]; y1 = ka1[9];
    __syncthreads();
    for (int kc = 0; kc < 32; kc++) {
        const int cur = kc & 1, nxt = cur ^ 1;
        if (kc < 31) {
            async_copy16(srcB + (size_t)(kc + 1) * 512 + tid,       &Bs[nxt][tid]);
            async_copy16(srcB + (size_t)(kc + 1) * 512 + tid + 256, &Bs[nxt][tid + 256]);
            As[nxt][tid]       = pack8(x0, y0);
            As[nxt][tid + 256] = pack8(x1, y1);
            if (kc < 30) {
                x0 = ka0[(kc + 2) * 8]; y0 = ka0[(kc + 2) * 8 + 1];
                x1 = ka1[(kc + 2) * 8]; y1 = ka1[(kc + 2) * 8 + 1];
            }
        }
        U4 af[4], bf[4];
#pragma unroll
        for (int mt = 0; mt < 4; mt++) af[mt].u = As[cur][(wm * 4 + mt) * 64 + lane];
#pragma unroll
        for (int nt = 0; nt < 4; nt++) bf[nt].u = Bs[cur][(wn * 4 + nt) * 64 + lane];
#pragma unroll
        for (int mt = 0; mt < 4; mt++)
#pragma unroll
            for (int nt = 0; nt < 4; nt++)
                acc[mt][nt] = __builtin_amdgcn_mfma_f32_16x16x32_bf16(
                    af[mt].b, bf[nt].b, acc[mt][nt], 0, 0, 0);
        __syncthreads();
    }
    const int col = lane & 15, qd = lane >> 4;
    float qv[4], vv[4];
#pragma unroll
    for (int nt = 0; nt < 4; nt++) {
        int n = nb * 128 + (wn * 4 + nt) * 16 + col;
        qv[nt] = qp[b * H + n];
        vv[nt] = Vaw[n];
    }
#pragma unroll
    for (int mt = 0; mt < 4; mt++) {
        float rs[4] = {0.f, 0.f, 0.f, 0.f};
#pragma unroll
        for (int nt = 0; nt < 4; nt++)
#pragma unroll
            for (int r = 0; r < 4; r++)
                rs[r] += ftanh(acc[mt][nt][r] + qv[nt]) * vv[nt];
#pragma unroll
        for (int r = 0; r < 4; r++) {
            float v = rs[r];
            v += __shfl_xor(v, 1, 64);
            v += __shfl_xor(v, 2, 64);
            v += __shfl_xor(v, 4, 64);
            v += __shfl_xor(v, 8, 64);
            if (col == 0) part[wn][wm * 64 + mt * 16 + qd * 4 + r] = v;
        }
    }
    __syncthreads();
    if (tid < 128)
        sp[(size_t)nb * B * S + b * S + s0 + tid] = part[0][tid] + part[1][tid];
}

__global__ __launch_bounds__(256) void k4_ctx_fb(const float* __restrict__ keys,
                                                 const float* __restrict__ sp,
                                                 float* __restrict__ out) {
    int sc = blockIdx.x, b = blockIdx.y;
    int t = threadIdx.x;
    __shared__ float red[256];
    __shared__ float wl[64];
    float v[8];
#pragma unroll
    for (int i = 0; i < 8; i++) {
        int s = i * 256 + t;
        float sum = 0.f;
#pragma unroll
        for (int nb = 0; nb < 8; nb++) sum += sp[(size_t)nb * B * S + b * S + s];
        v[i] = sum;
    }
    float lm = -1e30f;
#pragma unroll
    for (int i = 0; i < 8; i++) lm = fmaxf(lm, v[i]);
    red[t] = lm;
    __syncthreads();
    for (int s = 128; s > 0; s >>= 1) {
        if (t < s) red[t] = fmaxf(red[t], red[t + s]);
        __syncthreads();
    }
    float m = red[0];
    __syncthreads();
    float ls = 0.f;
#pragma unroll
    for (int i = 0; i < 8; i++) ls += __expf(v[i] - m);
    red[t] = ls;
    __syncthreads();
    for (int s = 128; s > 0; s >>= 1) {
        if (t < s) red[t] += red[t + s];
        __syncthreads();
    }
    float inv = 1.f / red[0];
    if (t < 64) {
        int s = sc * 64 + t;
        float sum = 0.f;
#pragma unroll
        for (int nb = 0; nb < 8; nb++) sum += sp[(size_t)nb * B * S + b * S + s];
        float w = __expf(sum - m) * inv;
        wl[t] = w;
        out[B * H + b * S + s] = w;
    }
    __syncthreads();
    const float4* kp = (const float4*)(keys + ((size_t)b * S + sc * 64) * H) + t;
    float4 acc = {0.f, 0.f, 0.f, 0.f};
#pragma unroll 8
    for (int s = 0; s < 64; s++) {
        float4 kv = kp[(size_t)s * 256];
        float w = wl[s];
        acc.x += w * kv.x; acc.y += w * kv.y;
        acc.z += w * kv.z; acc.w += w * kv.w;
    }
    float* dst = out + b * H + t * 4;
    atomicAdd(dst + 0, acc.x);
    atomicAdd(dst + 1, acc.y);
    atomicAdd(dst + 2, acc.z);
    atomicAdd(dst + 3, acc.w);
}

// ---------------------------------------------------------------------------
extern "C" void kernel_launch(void* const* d_in, const int* in_sizes, int n_in,
                              void* d_out, int out_size, void* d_ws, size_t ws_size,
                              hipStream_t stream) {
    const float* query = (const float*)d_in[0];
    const float* keys  = (const float*)d_in[1];
    const float* Wa_w  = (const float*)d_in[2];
    const float* Wa_b  = (const float*)d_in[3];
    const float* Ua_w  = (const float*)d_in[4];
    const float* Ua_b  = (const float*)d_in[5];
    const float* Va_w  = (const float*)d_in[6];
    float* out = (float*)d_out;

    // ws: [0,2MB) UaSw; [2MB,+128KB) qp; [2MB+128KB,+4MB) sp(16 planes); [8MB,+128MB) Abf
    uint4* UaSw = (uint4*)d_ws;
    float* qp = (float*)((char*)d_ws + (2u << 20));
    float* sp = (float*)((char*)d_ws + (2u << 20) + (128u << 10));
    uint4* Abf = (uint4*)((char*)d_ws + (8u << 20));
    const size_t NEED = (size_t)(8u << 20) + ((size_t)128u << 20);

    if (ws_size >= NEED) {
        static bool inited = false;
        if (!inited) {
            hipFuncSetAttribute(reinterpret_cast<const void*>(k2_scores3),
                                hipFuncAttributeMaxDynamicSharedMemorySize, 131072);
            inited = true;
        }
        ka_swz<<<32768, 256, 0, stream>>>(keys, Abf);
        k0_swizzle<<<512, 256, 0, stream>>>(Ua_w, UaSw);
        k1_qproj<<<dim3(16, B), 256, 0, stream>>>(query, Wa_w, Wa_b, Ua_b, qp);
        k2_scores3<<<1024, 512, 131072, stream>>>(Abf, UaSw, qp, Va_w, sp);
        k4_ctx2<<<dim3(8, B), 256, 0, stream>>>(Abf, sp, out);
    } else {
        hipMemsetAsync(d_out, 0, B * H * sizeof(float), stream);
        k0_swizzle<<<512, 256, 0, stream>>>(Ua_w, UaSw);
        k1_qproj<<<dim3(16, B), 256, 0, stream>>>(query, Wa_w, Wa_b, Ua_b, qp);
        k2_scores_fb<<<4096, 256, 0, stream>>>(keys, UaSw, qp, Va_w, sp);
        k4_ctx_fb<<<dim3(32, B), 256, 0, stream>>>(keys, sp, out);
    }
}

// Round 3
// 573.240 us; speedup vs baseline: 1.3066x; 1.3066x over previous
//
#include <hip/hip_runtime.h>
#include <hip/hip_bf16.h>

#define H 1024
#define B 32
#define S 2048

typedef __attribute__((ext_vector_type(8))) short bf16x8;
typedef __attribute__((ext_vector_type(4))) float f32x4;

union U4 { uint4 u; bf16x8 b; };

__device__ __forceinline__ unsigned short f2bf(float f) {
    unsigned u = __float_as_uint(f);
    unsigned r = (u + 0x7fffu + ((u >> 16) & 1u)) >> 16;
    return (unsigned short)r;
}

__device__ __forceinline__ uint4 pack8(float4 x, float4 y) {
    uint4 p;
    p.x = (unsigned)f2bf(x.x) | ((unsigned)f2bf(x.y) << 16);
    p.y = (unsigned)f2bf(x.z) | ((unsigned)f2bf(x.w) << 16);
    p.z = (unsigned)f2bf(y.x) | ((unsigned)f2bf(y.y) << 16);
    p.w = (unsigned)f2bf(y.z) | ((unsigned)f2bf(y.w) << 16);
    return p;
}

__device__ __forceinline__ float ftanh(float x) {
    float x2 = __builtin_amdgcn_fmed3f(x + x, -30.f, 30.f);
    float e = __expf(x2);
    return 1.f - 2.f * __builtin_amdgcn_rcpf(e + 1.f);
}

__device__ __forceinline__ void async_copy16(const void* g, void* l) {
    __builtin_amdgcn_global_load_lds(
        (const __attribute__((address_space(1))) unsigned int*)g,
        (__attribute__((address_space(3))) unsigned int*)l, 16, 0, 0);
}

// ---------------------------------------------------------------------------
// K0: Ua_w fp32 [n][k] -> bf16 MFMA-B-frag order: UaSw[nb(8)][kc(32)][nt(8)*64+lane]
__global__ void k0_swizzle(const float* __restrict__ Ua, uint4* __restrict__ UaSw) {
    int t = blockIdx.x * 256 + threadIdx.x;   // 0..131071
    int lane = t & 63;
    int nt = (t >> 6) & 7;
    int kc = (t >> 9) & 31;
    int nb = t >> 14;
    int n = nb * 128 + nt * 16 + (lane & 15);
    int k = kc * 32 + ((lane >> 4) & 3) * 8;
    const float4* src = (const float4*)(Ua + (size_t)n * H + k);
    UaSw[t] = pack8(src[0], src[1]);
}

// ---------------------------------------------------------------------------
// KA: keys fp32 [b*S+s][h] -> bf16 MFMA A-frag order:
// Abf[g], g = (stile*32 + kc)*64 + lane; stile = (b*S+s)/16
// row = stile*16 + (lane&15); col = kc*32 + ((lane>>4)&3)*8 + j
__global__ __launch_bounds__(256) void ka_swz(const float* __restrict__ keys,
                                              uint4* __restrict__ Abf) {
    size_t g = (size_t)blockIdx.x * 256 + threadIdx.x;   // 0..8388607
    int lane = (int)(g & 63);
    size_t u = g >> 6;
    int kc = (int)(u & 31);
    size_t stile = u >> 5;                                // 0..4095
    size_t row = stile * 16 + (lane & 15);
    int col = kc * 32 + ((lane >> 4) & 3) * 8;
    const float4* src = (const float4*)(keys + row * H + col);
    Abf[g] = pack8(src[0], src[1]);
}

// ---------------------------------------------------------------------------
// K1: qp[b][n] = sum_h query[b][h]*Wa_w[n][h] + Wa_b[n] + Ua_b[n]
__global__ __launch_bounds__(256) void k1_qproj(
    const float* __restrict__ q, const float* __restrict__ Wa,
    const float* __restrict__ Wab, const float* __restrict__ Uab,
    float* __restrict__ qp) {
    int b = blockIdx.y;
    int t = threadIdx.x;
    int n = blockIdx.x * 64 + (t >> 2);
    int quarter = t & 3;
    __shared__ float qs[H];
    for (int i = t; i < H; i += 256) qs[i] = q[b * H + i];
    __syncthreads();
    const float4* wr = (const float4*)(Wa + (size_t)n * H + quarter * 256);
    const float* qq = qs + quarter * 256;
    float acc = 0.f;
#pragma unroll 4
    for (int i = 0; i < 64; i++) {
        float4 w = wr[i];
        acc += qq[i * 4 + 0] * w.x + qq[i * 4 + 1] * w.y +
               qq[i * 4 + 2] * w.z + qq[i * 4 + 3] * w.w;
    }
    acc += __shfl_xor(acc, 1, 64);
    acc += __shfl_xor(acc, 2, 64);
    if (quarter == 0) qp[b * H + n] = acc + Wab[n] + Uab[n];
}

// ---------------------------------------------------------------------------
// K2v5: round-0 streaming GEMM + B-panel through LDS (counted-vmcnt pipeline).
// Block = 128 rows x 128 n (one nb), 4 waves, wave wm owns 2 m-tiles x 8 n-tiles
// (acc 2x8 f32x4 = 64 regs -> AGPR; PROVEN to fit at VGPR_Count 64, round 0).
// B tile per kc = 8 KB; 4 LDS buffers (32 KB), staged 3 ahead via
// global_load_lds (2 loads/thread/step). Boundary = sched_barrier(0) +
// s_waitcnt vmcnt(6) + raw s_barrier (B stages for t+2,t+3 + A(t+1) stay in
// flight; never vmcnt(0) in the loop). A stays a register stream (2 loads/kc,
// 1 ahead) -- its compiler-inserted wait lands at the na->ca copy and only
// drains loads older than A, preserving the B pipeline depth.
// Cuts B L2 traffic 4x (4.3 GB -> 1.07 GB); LDS frag reads are lane*16B
// linear (m97 pattern, conflict-free).
__global__ __launch_bounds__(256, 3) void k2_scores5(
    const uint4* __restrict__ Abf, const uint4* __restrict__ UaSw,
    const float* __restrict__ qp, const float* __restrict__ Vaw,
    float* __restrict__ sp) {
    __shared__ uint4 bbuf[4][512];   // 32 KB
    const int tid = threadIdx.x;
    const int lane = tid & 63;
    const int wm = tid >> 6;
    const int lid = blockIdx.x;      // 0..4095
    const int c = lid & 7;           // XCD slot (round-robin by linear id)
    const int qq = lid >> 3;
    const int nb = qq & 7;           // nb cycles fastest within an XCD
    const int mb = (qq >> 3) * 8 + c;
    const int b = mb >> 4;
    const int s0 = (mb & 15) << 7;

    const int stile0 = mb * 8 + wm * 2;
    const uint4* pa = Abf + (size_t)stile0 * 2048 + lane;   // kc stride 64, mt stride 2048
    const uint4* pbg = UaSw + (size_t)nb * 16384;           // kc stride 512

    f32x4 acc[2][8];
#pragma unroll
    for (int mt = 0; mt < 2; mt++)
#pragma unroll
        for (int nt = 0; nt < 8; nt++) acc[mt][nt] = (f32x4){0.f, 0.f, 0.f, 0.f};

    // prologue: A(0) first (so its dependent wait doesn't drain B stages),
    // then B tiles 0,1,2. Wait vmcnt(4) -> A(0)+B(0) landed, B(1),B(2) in flight.
    U4 ca[2];
    ca[0].u = pa[0];
    ca[1].u = pa[2048];
    async_copy16(pbg + tid,        &bbuf[0][tid]);
    async_copy16(pbg + 256 + tid,  &bbuf[0][tid + 256]);
    async_copy16(pbg + 512 + tid,  &bbuf[1][tid]);
    async_copy16(pbg + 768 + tid,  &bbuf[1][tid + 256]);
    async_copy16(pbg + 1024 + tid, &bbuf[2][tid]);
    async_copy16(pbg + 1280 + tid, &bbuf[2][tid + 256]);
    __builtin_amdgcn_sched_barrier(0);
    asm volatile("s_waitcnt vmcnt(4)" ::: "memory");
    __builtin_amdgcn_s_barrier();
    __builtin_amdgcn_sched_barrier(0);

#pragma unroll 4
    for (int t = 0; t < 32; t++) {
        // A prefetch for t+1 (registers); tail wraps to a redundant reload
        const int tn = (t + 1) & 31;
        U4 na0, na1;
        na0.u = pa[tn * 64];
        na1.u = pa[tn * 64 + 2048];

        // B stage for tile t+3 into buf (t+3)&3 == (t-1)&3 (read finished at
        // step t-1 before its barrier; issue here is after that barrier).
        const int ts = (t + 3) & 31;
        async_copy16(pbg + (size_t)ts * 512 + tid,       &bbuf[(t + 3) & 3][tid]);
        async_copy16(pbg + (size_t)ts * 512 + 256 + tid, &bbuf[(t + 3) & 3][tid + 256]);

        // B frags for tile t from LDS (landed: guaranteed by boundary t-1)
        U4 bb[8];
#pragma unroll
        for (int nt = 0; nt < 8; nt++) bb[nt].u = bbuf[t & 3][nt * 64 + lane];

        __builtin_amdgcn_s_setprio(1);
#pragma unroll
        for (int nt = 0; nt < 8; nt++)
#pragma unroll
            for (int mt = 0; mt < 2; mt++)
                acc[mt][nt] = __builtin_amdgcn_mfma_f32_16x16x32_bf16(
                    ca[mt].b, bb[nt].b, acc[mt][nt], 0, 0, 0);
        __builtin_amdgcn_s_setprio(0);
        ca[0] = na0;
        ca[1] = na1;

        // boundary: B(t+1) (issued 2 steps ago) guaranteed landed across ALL
        // waves once everyone passes; 6 newest ops (A(t+1), B(t+2), B(t+3))
        // stay in flight across the barrier.
        __builtin_amdgcn_sched_barrier(0);
        asm volatile("s_waitcnt vmcnt(6)" ::: "memory");
        __builtin_amdgcn_s_barrier();
        __builtin_amdgcn_sched_barrier(0);
    }
    asm volatile("s_waitcnt vmcnt(0)" ::: "memory");   // drain tail stages

    // epilogue: tanh, dot Va, shfl-reduce over col(16), direct store (disjoint rows)
    const int col = lane & 15, qd = lane >> 4;
    float qv[8], vv[8];
#pragma unroll
    for (int nt = 0; nt < 8; nt++) {
        int n = nb * 128 + nt * 16 + col;
        qv[nt] = qp[b * H + n];
        vv[nt] = Vaw[n];
    }
#pragma unroll
    for (int mt = 0; mt < 2; mt++) {
        float rs[4] = {0.f, 0.f, 0.f, 0.f};
#pragma unroll
        for (int nt = 0; nt < 8; nt++)
#pragma unroll
            for (int r = 0; r < 4; r++)
                rs[r] += ftanh(acc[mt][nt][r] + qv[nt]) * vv[nt];
#pragma unroll
        for (int r = 0; r < 4; r++) {
            float v = rs[r];
            v += __shfl_xor(v, 1, 64);
            v += __shfl_xor(v, 2, 64);
            v += __shfl_xor(v, 4, 64);
            v += __shfl_xor(v, 8, 64);
            if (col == 0)
                sp[(size_t)nb * B * S + b * S + s0 + wm * 32 + mt * 16 + qd * 4 + r] = v;
        }
    }
}

// ---------------------------------------------------------------------------
// K4v2: fused partial-sum + softmax + weights-write + context from bf16 keys.
// grid (8,32): block (kcg,b); wave wv handles kc=kcg*4+wv. Each (b,kc,q,j)
// owns unique context cols -> plain stores, no pre-zero needed.
__global__ __launch_bounds__(256) void k4_ctx2(const uint4* __restrict__ Abf,
                                               const float* __restrict__ sp,
                                               float* __restrict__ out) {
    int kcg = blockIdx.x, b = blockIdx.y;
    int t = threadIdx.x;
    __shared__ float red[256];
    __shared__ float wl[S];   // 8 KB

    float v[8];
#pragma unroll
    for (int i = 0; i < 8; i++) {
        int s = i * 256 + t;
        float sum = 0.f;
#pragma unroll
        for (int nb = 0; nb < 8; nb++) sum += sp[(size_t)nb * B * S + b * S + s];
        v[i] = sum;
    }
    float lm = -1e30f;
#pragma unroll
    for (int i = 0; i < 8; i++) lm = fmaxf(lm, v[i]);
    red[t] = lm;
    __syncthreads();
    for (int s = 128; s > 0; s >>= 1) {
        if (t < s) red[t] = fmaxf(red[t], red[t + s]);
        __syncthreads();
    }
    float m = red[0];
    __syncthreads();
    float ls = 0.f;
#pragma unroll
    for (int i = 0; i < 8; i++) ls += __expf(v[i] - m);
    red[t] = ls;
    __syncthreads();
    for (int s = 128; s > 0; s >>= 1) {
        if (t < s) red[t] += red[t + s];
        __syncthreads();
    }
    float inv = 1.f / red[0];
#pragma unroll
    for (int i = 0; i < 8; i++) {
        int s = i * 256 + t;
        float w = __expf(v[i] - m) * inv;
        wl[s] = w;
        if (kcg == 0) out[B * H + b * S + s] = w;
    }
    __syncthreads();

    const int wv = t >> 6, lane = t & 63, qd = lane >> 4, colr = lane & 15;
    const int kc = kcg * 4 + wv;
    float a8[8] = {0.f, 0.f, 0.f, 0.f, 0.f, 0.f, 0.f, 0.f};
    const uint4* base = Abf + ((size_t)(b * 128) * 32 + kc) * 64 + lane;
#pragma unroll 4
    for (int st = 0; st < 128; st++) {
        uint4 f = base[(size_t)st * 2048];
        float w = wl[st * 16 + colr];
        a8[0] += w * __uint_as_float(f.x << 16);
        a8[1] += w * __uint_as_float(f.x & 0xffff0000u);
        a8[2] += w * __uint_as_float(f.y << 16);
        a8[3] += w * __uint_as_float(f.y & 0xffff0000u);
        a8[4] += w * __uint_as_float(f.z << 16);
        a8[5] += w * __uint_as_float(f.z & 0xffff0000u);
        a8[6] += w * __uint_as_float(f.w << 16);
        a8[7] += w * __uint_as_float(f.w & 0xffff0000u);
    }
#pragma unroll
    for (int j = 0; j < 8; j++) {
        float vj = a8[j];
        vj += __shfl_xor(vj, 1, 64);
        vj += __shfl_xor(vj, 2, 64);
        vj += __shfl_xor(vj, 4, 64);
        vj += __shfl_xor(vj, 8, 64);
        a8[j] = vj;
    }
    if (colr == 0) {
        int colbase = kc * 32 + qd * 8;
#pragma unroll
        for (int j = 0; j < 8; j++) out[b * H + colbase + j] = a8[j];
    }
}

// ===========================================================================
// Fallback path (ws too small): round-4 kernels
// ===========================================================================
__global__ __launch_bounds__(256, 3) void k2_scores_fb(
    const float* __restrict__ keys, const uint4* __restrict__ UaSw,
    const float* __restrict__ qp, const float* __restrict__ Vaw,
    float* __restrict__ sp) {
    __shared__ uint4 As[2][512];
    __shared__ uint4 Bs[2][512];
    __shared__ float part[2][128];
    const int tid = threadIdx.x;
    const int lane = tid & 63;
    const int wave = tid >> 6;
    const int wm = wave >> 1, wn = wave & 1;
    const int lid = blockIdx.x;
    const int c = lid & 7;
    const int qq = lid >> 3;
    const int nb = qq & 7;
    const int mb = (qq >> 3) * 8 + c;
    const int b = mb >> 4;
    const int s0 = (mb & 15) << 7;
    const int el = tid & 63;
    const int srow0 = s0 + (tid >> 6) * 16 + (el & 15);
    const int srow1 = srow0 + 64;
    const int kofs = ((el >> 4) & 3) * 8;
    const float4* ka0 = (const float4*)(keys + ((size_t)b * S + srow0) * H + kofs);
    const float4* ka1 = (const float4*)(keys + ((size_t)b * S + srow1) * H + kofs);
    const uint4* srcB = UaSw + (size_t)nb * 32 * 512;
    f32x4 acc[4][4];
#pragma unroll
    for (int mt = 0; mt < 4; mt++)
#pragma unroll
        for (int nt = 0; nt < 4; nt++) acc[mt][nt] = (f32x4){0.f, 0.f, 0.f, 0.f};
    float4 x0 = ka0[0], y0 = ka0[1], x1 = ka1[0], y1 = ka1[1];
    async_copy16(srcB + tid,       &Bs[0][tid]);
    async_copy16(srcB + tid + 256, &Bs[0][tid + 256]);
    As[0][tid]       = pack8(x0, y0);
    As[0][tid + 256] = pack8(x1, y1);
    x0 = ka0[8]; y0 = ka0[9]; x1 = ka1[8]; y1 = ka1[9];
    __syncthreads();
    for (int kc = 0; kc < 32; kc++) {
        const int cur = kc & 1, nxt = cur ^ 1;
        if (kc < 31) {
            async_copy16(srcB + (size_t)(kc + 1) * 512 + tid,       &Bs[nxt][tid]);
            async_copy16(srcB + (size_t)(kc + 1) * 512 + tid + 256, &Bs[nxt][tid + 256]);
            As[nxt][tid]       = pack8(x0, y0);
            As[nxt][tid + 256] = pack8(x1, y1);
            if (kc < 30) {
                x0 = ka0[(kc + 2) * 8]; y0 = ka0[(kc + 2) * 8 + 1];
                x1 = ka1[(kc + 2) * 8]; y1 = ka1[(kc + 2) * 8 + 1];
            }
        }
        U4 af[4], bf[4];
#pragma unroll
        for (int mt = 0; mt < 4; mt++) af[mt].u = As[cur][(wm * 4 + mt) * 64 + lane];
#pragma unroll
        for (int nt = 0; nt < 4; nt++) bf[nt].u = Bs[cur][(wn * 4 + nt) * 64 + lane];
#pragma unroll
        for (int mt = 0; mt < 4; mt++)
#pragma unroll
            for (int nt = 0; nt < 4; nt++)
                acc[mt][nt] = __builtin_amdgcn_mfma_f32_16x16x32_bf16(
                    af[mt].b, bf[nt].b, acc[mt][nt], 0, 0, 0);
        __syncthreads();
    }
    const int col = lane & 15, qd = lane >> 4;
    float qv[4], vv[4];
#pragma unroll
    for (int nt = 0; nt < 4; nt++) {
        int n = nb * 128 + (wn * 4 + nt) * 16 + col;
        qv[nt] = qp[b * H + n];
        vv[nt] = Vaw[n];
    }
#pragma unroll
    for (int mt = 0; mt < 4; mt++) {
        float rs[4] = {0.f, 0.f, 0.f, 0.f};
#pragma unroll
        for (int nt = 0; nt < 4; nt++)
#pragma unroll
            for (int r = 0; r < 4; r++)
                rs[r] += ftanh(acc[mt][nt][r] + qv[nt]) * vv[nt];
#pragma unroll
        for (int r = 0; r < 4; r++) {
            float v = rs[r];
            v += __shfl_xor(v, 1, 64);
            v += __shfl_xor(v, 2, 64);
            v += __shfl_xor(v, 4, 64);
            v += __shfl_xor(v, 8, 64);
            if (col == 0) part[wn][wm * 64 + mt * 16 + qd * 4 + r] = v;
        }
    }
    __syncthreads();
    if (tid < 128)
        sp[(size_t)nb * B * S + b * S + s0 + tid] = part[0][tid] + part[1][tid];
}

__global__ __launch_bounds__(256) void k4_ctx_fb(const float* __restrict__ keys,
                                                 const float* __restrict__ sp,
                                                 float* __restrict__ out) {
    int sc = blockIdx.x, b = blockIdx.y;
    int t = threadIdx.x;
    __shared__ float red[256];
    __shared__ float wl[64];
    float v[8];
#pragma unroll
    for (int i = 0; i < 8; i++) {
        int s = i * 256 + t;
        float sum = 0.f;
#pragma unroll
        for (int nb = 0; nb < 8; nb++) sum += sp[(size_t)nb * B * S + b * S + s];
        v[i] = sum;
    }
    float lm = -1e30f;
#pragma unroll
    for (int i = 0; i < 8; i++) lm = fmaxf(lm, v[i]);
    red[t] = lm;
    __syncthreads();
    for (int s = 128; s > 0; s >>= 1) {
        if (t < s) red[t] = fmaxf(red[t], red[t + s]);
        __syncthreads();
    }
    float m = red[0];
    __syncthreads();
    float ls = 0.f;
#pragma unroll
    for (int i = 0; i < 8; i++) ls += __expf(v[i] - m);
    red[t] = ls;
    __syncthreads();
    for (int s = 128; s > 0; s >>= 1) {
        if (t < s) red[t] += red[t + s];
        __syncthreads();
    }
    float inv = 1.f / red[0];
    if (t < 64) {
        int s = sc * 64 + t;
        float sum = 0.f;
#pragma unroll
        for (int nb = 0; nb < 8; nb++) sum += sp[(size_t)nb * B * S + b * S + s];
        float w = __expf(sum - m) * inv;
        wl[t] = w;
        out[B * H + b * S + s] = w;
    }
    __syncthreads();
    const float4* kp = (const float4*)(keys + ((size_t)b * S + sc * 64) * H) + t;
    float4 acc = {0.f, 0.f, 0.f, 0.f};
#pragma unroll 8
    for (int s = 0; s < 64; s++) {
        float4 kv = kp[(size_t)s * 256];
        float w = wl[s];
        acc.x += w * kv.x; acc.y += w * kv.y;
        acc.z += w * kv.z; acc.w += w * kv.w;
    }
    float* dst = out + b * H + t * 4;
    atomicAdd(dst + 0, acc.x);
    atomicAdd(dst + 1, acc.y);
    atomicAdd(dst + 2, acc.z);
    atomicAdd(dst + 3, acc.w);
}

// ---------------------------------------------------------------------------
extern "C" void kernel_launch(void* const* d_in, const int* in_sizes, int n_in,
                              void* d_out, int out_size, void* d_ws, size_t ws_size,
                              hipStream_t stream) {
    const float* query = (const float*)d_in[0];
    const float* keys  = (const float*)d_in[1];
    const float* Wa_w  = (const float*)d_in[2];
    const float* Wa_b  = (const float*)d_in[3];
    const float* Ua_w  = (const float*)d_in[4];
    const float* Ua_b  = (const float*)d_in[5];
    const float* Va_w  = (const float*)d_in[6];
    float* out = (float*)d_out;

    // ws: [0,2MB) UaSw; [2MB,+128KB) qp; [2MB+128KB,+2MB) sp; [8MB,+128MB) Abf
    uint4* UaSw = (uint4*)d_ws;
    float* qp = (float*)((char*)d_ws + (2u << 20));
    float* sp = (float*)((char*)d_ws + (2u << 20) + (128u << 10));
    uint4* Abf = (uint4*)((char*)d_ws + (8u << 20));
    const size_t NEED = (size_t)(8u << 20) + ((size_t)128u << 20);

    if (ws_size >= NEED) {
        ka_swz<<<32768, 256, 0, stream>>>(keys, Abf);
        k0_swizzle<<<512, 256, 0, stream>>>(Ua_w, UaSw);
        k1_qproj<<<dim3(16, B), 256, 0, stream>>>(query, Wa_w, Wa_b, Ua_b, qp);
        k2_scores5<<<4096, 256, 0, stream>>>(Abf, UaSw, qp, Va_w, sp);
        k4_ctx2<<<dim3(8, B), 256, 0, stream>>>(Abf, sp, out);
    } else {
        hipMemsetAsync(d_out, 0, B * H * sizeof(float), stream);
        k0_swizzle<<<512, 256, 0, stream>>>(Ua_w, UaSw);
        k1_qproj<<<dim3(16, B), 256, 0, stream>>>(query, Wa_w, Wa_b, Ua_b, qp);
        k2_scores_fb<<<4096, 256, 0, stream>>>(keys, UaSw, qp, Va_w, sp);
        k4_ctx_fb<<<dim3(32, B), 256, 0, stream>>>(keys, sp, out);
    }
}